// Round 6
// baseline (203.930 us; speedup 1.0000x reference)
//
#include <hip/hip_runtime.h>

#define BN 256   // batches
#define NN 256   // matrix dim
#define WL 8     // walk length

typedef __attribute__((ext_vector_type(4))) float f32x4;
typedef unsigned long long ull;

// ---- f32 -> fp8 e4m3fn (OCP), RNE; manual fallback if builtin absent -------
__device__ inline unsigned f2e4m3(float x) {
  union { float f; unsigned u; } v; v.f = x;
  if (v.f <= 0.0f) return 0;                       // inputs are >= 0 here
  int e = (int)((v.u >> 23) & 0xff) - 127;
  if (e < -9) return 0;
  if (e < -6) {                                    // subnormal: q = RNE(x*512)
    int qi = (int)(x * 512.0f + 0.5f);
    return qi > 7 ? 7u : (unsigned)qi;
  }
  unsigned r = v.u + 0x7ffff + ((v.u >> 20) & 1);  // RNE to 3 mantissa bits
  e = (int)((r >> 23) & 0xff) - 127;
  unsigned m = (r >> 20) & 7;
  return (unsigned)(((e + 7) << 3) | m);
}

__device__ inline unsigned pk4(float a, float b, float c, float d) {
#if __has_builtin(__builtin_amdgcn_cvt_pk_fp8_f32)
  int r = 0;
  r = __builtin_amdgcn_cvt_pk_fp8_f32(a, b, r, false);   // bytes 0,1
  r = __builtin_amdgcn_cvt_pk_fp8_f32(c, d, r, true);    // bytes 2,3
  return (unsigned)r;
#else
  return f2e4m3(a) | (f2e4m3(b) << 8) | (f2e4m3(c) << 16) | (f2e4m3(d) << 24);
#endif
}

// ---- fused kernel: one block (8 waves) per batch ---------------------------
// LDS: S = 64*P, fp8 e4m3, row-major with 8B-granule XOR swizzle:
//   byte(row,col) at row*256 + ((col>>3) ^ (row&31))*8 + (col&7)
// A-frag ds_read_b64 and prep ds_write_b32 are conflict-free; exactly 64 KB.
//
// Chain: bcur holds 64*P^{g-1} as fp8 B-frags (g=1: identity, unscaled).
// Step g: acc = S*bcur = 4096*P^g (64*P for g=1); diag = acc/4096;
// bnext = fp8(acc/64). mt-pair loop: bnext[lnt][pt] depends only on acc
// tiles {2pt, 2pt+1}, so each pair's acc retires into its B-frag via 8
// bpermutes right after its 32 MFMAs. No barriers after the first, no
// global traffic except in/out.
//
// __launch_bounds__(512, 1): grid = 1 block/CU (256 blocks, 256 CUs), so
// 2 blocks/CU never happens -- take the full 256 VGPR/wave budget instead.
// At (512,2)/128 VGPR the allocator spilled ~18 dw/lane/step = ~130 MB of
// scratch HBM churn (R5 counters: WRITE 68 MB, FETCH +120 MB) and the spill
// loads dominated the critical path (MfmaUtil 17%).
__global__ __launch_bounds__(512, 1) void k_chain(const float* __restrict__ A,
                                                  float* __restrict__ out) {
  __shared__ unsigned char S[65536];
  int b  = blockIdx.x;
  int t  = threadIdx.x;
  int wi = t >> 6;                 // wave 0..7
  int l  = t & 63;
  int q  = l >> 4, l16 = l & 15;
  const float* Ab = A + (size_t)b * NN * NN;
  float* outb = out + (size_t)b * NN * WL;

  // ---- phase 1: prep. wave wi handles rows [32wi, 32wi+32).
  for (int r0 = wi * 32; r0 < wi * 32 + 32; r0 += 8) {
    float4 rv[8];                                   // 8-deep load pipeline
    #pragma unroll
    for (int i = 0; i < 8; i++)
      rv[i] = *(const float4*)(Ab + (size_t)(r0 + i) * NN + l * 4);
    #pragma unroll
    for (int i = 0; i < 8; i++) {
      int row = r0 + i;                             // wave-uniform
      float t0 = rv[i].x > 0.3f ? rv[i].x : 0.0f;
      float t1 = rv[i].y > 0.3f ? rv[i].y : 0.0f;
      float t2 = rv[i].z > 0.3f ? rv[i].z : 0.0f;
      float t3 = rv[i].w > 0.3f ? rv[i].w : 0.0f;
      float s = (t0 + t1) + (t2 + t3);
      #pragma unroll
      for (int o = 32; o; o >>= 1) s += __shfl_xor(s, o);
      float dinv = s > 0.0f ? 1.0f / s : 0.0f;
      int rm = row & 3;                             // uniform
      float tv = rm == 0 ? t0 : rm == 1 ? t1 : rm == 2 ? t2 : t3;
      if (l == (row >> 2)) {
        outb[row * WL + 0] = 1.0f;
        outb[row * WL + 1] = tv * dinv;             // diag(P), exact f32
      }
      float sc = dinv * 64.0f;                      // store S = 64*P
      unsigned pkd = pk4(t0 * sc, t1 * sc, t2 * sc, t3 * sc);
      unsigned addr = row * 256 + ((((unsigned)l >> 1) ^ (row & 31)) << 3) + ((l & 1) << 2);
      *(unsigned*)&S[addr] = pkd;
    }
  }
  __syncthreads();   // S complete; read-only hereafter

  // ---- phase 2: identity B-frags (X0 = I). B[k][n]=1 iff k==n,
  // n = 32wi+16lnt+l16, k = 32kt+8q+j  ->  kt==wi, q==2lnt+(l16>>3), j=l16&7.
  long bcur[2][8], bnext[2][8];
  #pragma unroll
  for (int lnt = 0; lnt < 2; lnt++)
    #pragma unroll
    for (int kt = 0; kt < 8; kt++)
      bcur[lnt][kt] = (kt == wi && q == 2 * lnt + (l16 >> 3))
                        ? (long)(0x38ull << (8 * (l16 & 7)))   // e4m3 1.0
                        : 0L;

  // ---- phase 3: chain, mt-pair structured.
  const float invQ = 1.0f / 4096.0f;
  const float inv64 = 1.0f / 64.0f;
  for (int g = 1; g <= 7; g++) {
    float osc = (g == 1) ? 1.0f : inv64;            // bnext scale
    #pragma unroll
    for (int pt = 0; pt < 8; pt++) {                // tiles mt = 2pt, 2pt+1
      f32x4 acc[2][2];
      acc[0][0] = (f32x4){0.f, 0.f, 0.f, 0.f};
      acc[0][1] = (f32x4){0.f, 0.f, 0.f, 0.f};
      acc[1][0] = (f32x4){0.f, 0.f, 0.f, 0.f};
      acc[1][1] = (f32x4){0.f, 0.f, 0.f, 0.f};
      int row0 = 32 * pt + l16;
      int row1 = row0 + 16;
      #pragma unroll
      for (int kt = 0; kt < 8; kt++) {
        long a0 = *(const long*)&S[row0 * 256 + (((4 * kt + q) ^ (row0 & 31)) << 3)];
        long a1 = *(const long*)&S[row1 * 256 + (((4 * kt + q) ^ (row1 & 31)) << 3)];
        acc[0][0] = __builtin_amdgcn_mfma_f32_16x16x32_fp8_fp8(a0, bcur[0][kt], acc[0][0], 0, 0, 0);
        acc[0][1] = __builtin_amdgcn_mfma_f32_16x16x32_fp8_fp8(a0, bcur[1][kt], acc[0][1], 0, 0, 0);
        acc[1][0] = __builtin_amdgcn_mfma_f32_16x16x32_fp8_fp8(a1, bcur[0][kt], acc[1][0], 0, 0, 0);
        acc[1][1] = __builtin_amdgcn_mfma_f32_16x16x32_fp8_fp8(a1, bcur[1][kt], acc[1][1], 0, 0, 0);
      }
      // diag(P^g): C layout col=l16, row=4q+r. Diagonal tiles: pt==wi,
      // tile 2pt <-> lnt=0 (acc[0][0]), tile 2pt+1 <-> lnt=1 (acc[1][1]).
      if (g >= 2 && pt == wi && (l16 >> 2) == q) {
        int r = l16 & 3;
        outb[(32 * pt + l16) * WL + g]      = acc[0][0][r] * invQ;
        outb[(32 * pt + 16 + l16) * WL + g] = acc[1][1][r] * invQ;
      }
      if (g < 7) {
        // acc -> bnext[.][pt]: frag dword d, quad q needs tile 2pt+(q>>1),
        // source quad_c = 2(q&1)+d, same l16.
        unsigned pkv[2][2];
        #pragma unroll
        for (int mtl = 0; mtl < 2; mtl++)
          #pragma unroll
          for (int lnt = 0; lnt < 2; lnt++)
            pkv[mtl][lnt] = pk4(acc[mtl][lnt][0] * osc, acc[mtl][lnt][1] * osc,
                                acc[mtl][lnt][2] * osc, acc[mtl][lnt][3] * osc);
        int src0 = ((q & 1) << 5) | l16;   // quad_c = 2(q&1)
        int src1 = src0 + 16;              // quad_c = 2(q&1)+1
        int hiq = q >> 1;
        #pragma unroll
        for (int lnt = 0; lnt < 2; lnt++) {
          unsigned lo0 = (unsigned)__shfl((int)pkv[0][lnt], src0);
          unsigned hi0 = (unsigned)__shfl((int)pkv[1][lnt], src0);
          unsigned lo1 = (unsigned)__shfl((int)pkv[0][lnt], src1);
          unsigned hi1 = (unsigned)__shfl((int)pkv[1][lnt], src1);
          unsigned d0 = hiq ? hi0 : lo0;
          unsigned d1 = hiq ? hi1 : lo1;
          bnext[lnt][pt] = (long)(((ull)d1 << 32) | d0);
        }
      }
    }
    if (g < 7) {
      #pragma unroll
      for (int lnt = 0; lnt < 2; lnt++)
        #pragma unroll
        for (int kt = 0; kt < 8; kt++)
          bcur[lnt][kt] = bnext[lnt][kt];
    }
  }
}

extern "C" void kernel_launch(void* const* d_in, const int* in_sizes, int n_in,
                              void* d_out, int out_size, void* d_ws, size_t ws_size,
                              hipStream_t stream) {
  const float* A = (const float*)d_in[0];
  float* out = (float*)d_out;
  k_chain<<<BN, 512, 0, stream>>>(A, out);
}

// Round 7
// 133.872 us; speedup vs baseline: 1.5233x; 1.5233x over previous
//
#include <hip/hip_runtime.h>

#define BN 256   // batches
#define NN 256   // matrix dim
#define WL 8     // walk length

typedef __attribute__((ext_vector_type(4))) float f32x4;
typedef unsigned long long ull;

// Segment fence: kills LICM/hoisting of LDS loads across it (all memory
// appears clobbered), keeping the ds_read in-flight window small. Without
// this, all 128 A-frag ds_read_b64 are g-loop-invariant (S is read-only
// after the barrier) and LICM hoists ~256 VGPRs of A-frags out of the
// g-loop -> spill -> the 120 MB scratch fetch seen in R5/R6 counters.
#define SEG_FENCE() __asm__ volatile("" ::: "memory")

// ---- f32 -> fp8 e4m3fn (OCP), RNE; manual fallback if builtin absent -------
__device__ inline unsigned f2e4m3(float x) {
  union { float f; unsigned u; } v; v.f = x;
  if (v.f <= 0.0f) return 0;                       // inputs are >= 0 here
  int e = (int)((v.u >> 23) & 0xff) - 127;
  if (e < -9) return 0;
  if (e < -6) {                                    // subnormal: q = RNE(x*512)
    int qi = (int)(x * 512.0f + 0.5f);
    return qi > 7 ? 7u : (unsigned)qi;
  }
  unsigned r = v.u + 0x7ffff + ((v.u >> 20) & 1);  // RNE to 3 mantissa bits
  e = (int)((r >> 23) & 0xff) - 127;
  unsigned m = (r >> 20) & 7;
  return (unsigned)(((e + 7) << 3) | m);
}

__device__ inline unsigned pk4(float a, float b, float c, float d) {
#if __has_builtin(__builtin_amdgcn_cvt_pk_fp8_f32)
  int r = 0;
  r = __builtin_amdgcn_cvt_pk_fp8_f32(a, b, r, false);   // bytes 0,1
  r = __builtin_amdgcn_cvt_pk_fp8_f32(c, d, r, true);    // bytes 2,3
  return (unsigned)r;
#else
  return f2e4m3(a) | (f2e4m3(b) << 8) | (f2e4m3(c) << 16) | (f2e4m3(d) << 24);
#endif
}

// ---- fused kernel: one block (8 waves) per batch ---------------------------
// LDS: S = 64*P, fp8 e4m3, row-major with 8B-granule XOR swizzle:
//   byte(row,col) at row*256 + ((col>>3) ^ (row&31))*8 + (col&7)
// A-frag ds_read_b64 and prep ds_write_b32 are conflict-free; exactly 64 KB.
//
// Chain: bcur holds 64*P^{g-1} as fp8 B-frags (g=1: identity, unscaled).
// Step g: acc = S*bcur = 4096*P^g (64*P for g=1); diag = acc/4096;
// bnext = fp8(acc/64). mt-pair loop: bnext[lnt][pt] depends only on acc
// tiles {2pt, 2pt+1}, so each pair's acc retires into its B-frag via 8
// shuffles right after its 32 MFMAs. No barriers after the first, no
// global traffic except in/out.
__global__ __launch_bounds__(512, 1) void k_chain(const float* __restrict__ A,
                                                  float* __restrict__ out) {
  __shared__ unsigned char S[65536];
  int b  = blockIdx.x;
  int t  = threadIdx.x;
  int wi = t >> 6;                 // wave 0..7
  int l  = t & 63;
  int q  = l >> 4, l16 = l & 15;
  const float* Ab = A + (size_t)b * NN * NN;
  float* outb = out + (size_t)b * NN * WL;

  // ---- phase 1: prep. wave wi handles rows [32wi, 32wi+32).
  for (int r0 = wi * 32; r0 < wi * 32 + 32; r0 += 8) {
    float4 rv[8];                                   // 8-deep load pipeline
    #pragma unroll
    for (int i = 0; i < 8; i++)
      rv[i] = *(const float4*)(Ab + (size_t)(r0 + i) * NN + l * 4);
    #pragma unroll
    for (int i = 0; i < 8; i++) {
      int row = r0 + i;                             // wave-uniform
      float t0 = rv[i].x > 0.3f ? rv[i].x : 0.0f;
      float t1 = rv[i].y > 0.3f ? rv[i].y : 0.0f;
      float t2 = rv[i].z > 0.3f ? rv[i].z : 0.0f;
      float t3 = rv[i].w > 0.3f ? rv[i].w : 0.0f;
      float s = (t0 + t1) + (t2 + t3);
      #pragma unroll
      for (int o = 32; o; o >>= 1) s += __shfl_xor(s, o);
      float dinv = s > 0.0f ? 1.0f / s : 0.0f;
      int rm = row & 3;                             // uniform
      float tv = rm == 0 ? t0 : rm == 1 ? t1 : rm == 2 ? t2 : t3;
      if (l == (row >> 2)) {
        outb[row * WL + 0] = 1.0f;
        outb[row * WL + 1] = tv * dinv;             // diag(P), exact f32
      }
      float sc = dinv * 64.0f;                      // store S = 64*P
      unsigned pkd = pk4(t0 * sc, t1 * sc, t2 * sc, t3 * sc);
      unsigned addr = row * 256 + ((((unsigned)l >> 1) ^ (row & 31)) << 3) + ((l & 1) << 2);
      *(unsigned*)&S[addr] = pkd;
    }
  }
  __syncthreads();   // S complete; read-only hereafter

  // ---- phase 2: identity B-frags (X0 = I). B[k][n]=1 iff k==n,
  // n = 32wi+16lnt+l16, k = 32kt+8q+j  ->  kt==wi, q==2lnt+(l16>>3), j=l16&7.
  long bcur[2][8], bnext[2][8];
  #pragma unroll
  for (int lnt = 0; lnt < 2; lnt++)
    #pragma unroll
    for (int kt = 0; kt < 8; kt++)
      bcur[lnt][kt] = (kt == wi && q == 2 * lnt + (l16 >> 3))
                        ? (long)(0x38ull << (8 * (l16 & 7)))   // e4m3 1.0
                        : 0L;

  // ---- phase 3: chain, mt-pair structured. g-loop MUST stay rolled and
  // fenced so the 128 per-step A-frag loads are re-issued per segment
  // instead of hoisted (see SEG_FENCE comment).
  const float invQ = 1.0f / 4096.0f;
  const float inv64 = 1.0f / 64.0f;
  #pragma unroll 1
  for (int g = 1; g <= 7; g++) {
    float osc = (g == 1) ? 1.0f : inv64;            // bnext scale
    #pragma unroll
    for (int pt = 0; pt < 8; pt++) {                // tiles mt = 2pt, 2pt+1
      SEG_FENCE();
      f32x4 acc[2][2];
      acc[0][0] = (f32x4){0.f, 0.f, 0.f, 0.f};
      acc[0][1] = (f32x4){0.f, 0.f, 0.f, 0.f};
      acc[1][0] = (f32x4){0.f, 0.f, 0.f, 0.f};
      acc[1][1] = (f32x4){0.f, 0.f, 0.f, 0.f};
      int row0 = 32 * pt + l16;
      int row1 = row0 + 16;
      #pragma unroll
      for (int kt = 0; kt < 8; kt++) {
        long a0 = *(const long*)&S[row0 * 256 + (((4 * kt + q) ^ (row0 & 31)) << 3)];
        long a1 = *(const long*)&S[row1 * 256 + (((4 * kt + q) ^ (row1 & 31)) << 3)];
        acc[0][0] = __builtin_amdgcn_mfma_f32_16x16x32_fp8_fp8(a0, bcur[0][kt], acc[0][0], 0, 0, 0);
        acc[0][1] = __builtin_amdgcn_mfma_f32_16x16x32_fp8_fp8(a0, bcur[1][kt], acc[0][1], 0, 0, 0);
        acc[1][0] = __builtin_amdgcn_mfma_f32_16x16x32_fp8_fp8(a1, bcur[0][kt], acc[1][0], 0, 0, 0);
        acc[1][1] = __builtin_amdgcn_mfma_f32_16x16x32_fp8_fp8(a1, bcur[1][kt], acc[1][1], 0, 0, 0);
      }
      // diag(P^g): C layout col=l16, row=4q+r. Diagonal tiles: pt==wi,
      // tile 2pt <-> lnt=0 (acc[0][0]), tile 2pt+1 <-> lnt=1 (acc[1][1]).
      if (g >= 2 && pt == wi && (l16 >> 2) == q) {
        int r = l16 & 3;
        outb[(32 * pt + l16) * WL + g]      = acc[0][0][r] * invQ;
        outb[(32 * pt + 16 + l16) * WL + g] = acc[1][1][r] * invQ;
      }
      if (g < 7) {
        // acc -> bnext[.][pt]: frag dword d, quad q needs tile 2pt+(q>>1),
        // source quad_c = 2(q&1)+d, same l16.
        unsigned pkv[2][2];
        #pragma unroll
        for (int mtl = 0; mtl < 2; mtl++)
          #pragma unroll
          for (int lnt = 0; lnt < 2; lnt++)
            pkv[mtl][lnt] = pk4(acc[mtl][lnt][0] * osc, acc[mtl][lnt][1] * osc,
                                acc[mtl][lnt][2] * osc, acc[mtl][lnt][3] * osc);
        int src0 = ((q & 1) << 5) | l16;   // quad_c = 2(q&1)
        int src1 = src0 + 16;              // quad_c = 2(q&1)+1
        int hiq = q >> 1;
        #pragma unroll
        for (int lnt = 0; lnt < 2; lnt++) {
          unsigned lo0 = (unsigned)__shfl((int)pkv[0][lnt], src0);
          unsigned hi0 = (unsigned)__shfl((int)pkv[1][lnt], src0);
          unsigned lo1 = (unsigned)__shfl((int)pkv[0][lnt], src1);
          unsigned hi1 = (unsigned)__shfl((int)pkv[1][lnt], src1);
          unsigned d0 = hiq ? hi0 : lo0;
          unsigned d1 = hiq ? hi1 : lo1;
          bnext[lnt][pt] = (long)(((ull)d1 << 32) | d0);
        }
      }
    }
    if (g < 7) {
      #pragma unroll
      for (int lnt = 0; lnt < 2; lnt++)
        #pragma unroll
        for (int kt = 0; kt < 8; kt++)
          bcur[lnt][kt] = bnext[lnt][kt];
    }
  }
}

extern "C" void kernel_launch(void* const* d_in, const int* in_sizes, int n_in,
                              void* d_out, int out_size, void* d_ws, size_t ws_size,
                              hipStream_t stream) {
  const float* A = (const float*)d_in[0];
  float* out = (float*)d_out;
  k_chain<<<BN, 512, 0, stream>>>(A, out);
}